// Round 14
// baseline (445.021 us; speedup 1.0000x reference)
//
#include <hip/hip_runtime.h>
#include <math.h>

#define E 1152
#define H 16
#define HD 72
#define B 32
#define S 4096
#define IDIM 4304
#define NSL 16

#define NEGF (-3.402823466e38f)
#define SCALE 0.1178511301977579f  // 1/sqrt(72)

typedef short short8 __attribute__((ext_vector_type(8)));
typedef float f32x4 __attribute__((ext_vector_type(4)));
typedef unsigned int uint4v __attribute__((ext_vector_type(4)));

#define LGKM_BAR() do { asm volatile("s_waitcnt lgkmcnt(0)" ::: "memory"); \
                        __builtin_amdgcn_s_barrier(); } while(0)

__device__ __forceinline__ unsigned int cvtpk_bf16(float lo, float hi){
  unsigned int r;
  asm("v_cvt_pk_bf16_f32 %0, %1, %2" : "=v"(r) : "v"(lo), "v"(hi));
  return r;
}

__device__ __forceinline__ unsigned short f2bf(float x){
  unsigned int u = __float_as_uint(x);
  u = (u + 0x7fffu + ((u >> 16) & 1u)) >> 16;   // RNE
  return (unsigned short)u;
}

// bf16 tile dest byte offset for staging slot f (float4 units); rematerializable
__device__ __forceinline__ int dst_off_f(int f){
  int r = f / 288;
  int c4 = f - r*288;
  return ((r>>2)*72 + (c4>>2))*128 + (r&3)*32 + (c4&3)*8;
}

__device__ __forceinline__ float wredsum(float v){
  v += __shfl_xor(v,32); v += __shfl_xor(v,16); v += __shfl_xor(v,8);
  v += __shfl_xor(v,4);  v += __shfl_xor(v,2);  v += __shfl_xor(v,1);
  return v;
}

// q[j] = probe . wq[j,:] + bq[j]   (float2 loads)
__global__ void k_q(const float* __restrict__ probe, const float* __restrict__ ipw,
                    const float* __restrict__ ipb, float* __restrict__ q){
  int tid = threadIdx.x, lane = tid & 63, w = tid >> 6;
  int j = blockIdx.x*4 + w;
  const float2* wr = (const float2*)(ipw + (size_t)j*E);
  const float2* pr = (const float2*)probe;
  float s = 0.f;
  #pragma unroll
  for (int t=0;t<9;++t){
    int e2 = lane + 64*t;
    float2 a = pr[e2], b = wr[e2];
    s = fmaf(a.x, b.x, fmaf(a.y, b.y, s));
  }
  s = wredsum(s);
  if (lane==0) q[j] = s + ipb[j];
}

// qk[h][e] -> bf16 B-frag order: kk = e>>5, lane = ((e>>3)&3)*16 + h, j = e&7
__global__ void k_qk(const float* __restrict__ q, const float* __restrict__ ipw,
                     const float* __restrict__ ipb, unsigned short* __restrict__ qkfrag,
                     float* __restrict__ cb){
  int idx = blockIdx.x*256 + threadIdx.x;   // < H*E
  int h = idx / E, e = idx % E;
  float s = 0.f;
  #pragma unroll 8
  for (int d=0; d<HD; ++d)
    s = fmaf(q[h*HD+d], ipw[(size_t)(E + h*HD + d)*E + e], s);
  int kk = e >> 5, g = (e >> 3) & 3, j = e & 7;
  qkfrag[(size_t)kk*512 + (g*16 + h)*8 + j] = f2bf(s);
  if (idx < H){
    float c = 0.f;
    for (int d=0; d<HD; ++d) c = fmaf(q[idx*HD+d], ipb[E + idx*HD + d], c);
    cb[idx] = c;
  }
}

// ---------------- fused flash pass, v6: producer/consumer wave specialization.
// 512 threads / 8 waves; waves 0-3 = compute (QK+softmax+PV/2),
// waves 4-7 = memory (staging 18 slots each, 2 batches; + PV/2).
// uni0/uni1 are role-unioned register arrays (qkf | staging batches) so the
// static VGPR footprint stays <=128 -> 4 waves/SIMD, 2 blocks/CU.
__global__ __launch_bounds__(512, 4) void k_fused(
    const float* __restrict__ hidden, const unsigned short* __restrict__ qkfrag,
    const float* __restrict__ cb, const int* __restrict__ mask,
    float* __restrict__ part, float* __restrict__ part_ml){
  __shared__ __attribute__((aligned(16))) char smem[79680];
  float*    D1      = (float*)(smem + 73728);       // [4][16][17]
  float*    f_lds   = (float*)(smem + 78080);       // [16]
  unsigned* wgtA    = (unsigned*)(smem + 78144);    // [4][16][2]
  float*    mask_lds= (float*)(smem + 78656);       // [256]

  int tid = threadIdx.x, lane = tid & 63, w = tid >> 6;  // w = 0..7
  int b = blockIdx.x >> 4, sl = blockIdx.x & 15;
  int s0 = sl * 256;
  int qt = w & 3, half = w >> 2;
  int il = tid & 255;                 // staging lane id (waves 4-7)

  if (tid < 256)
    mask_lds[tid] = (1.0f - (float)mask[(size_t)b*S + s0 + tid]) * NEGF;

  uint4v uni0[9], uni1[9];            // compute: uni0 = qkf. memory: batches.
  const float* hbase = hidden + ((size_t)b*S + s0)*E;

  if (w < 4){
    const uint4v* qf = (const uint4v*)qkfrag;
    #pragma unroll
    for (int kk=0;kk<9;++kk) uni0[kk] = qf[(9*w + kk)*64 + lane];
  }

  int rA = lane & 15, gA = lane >> 4;
  int aoff = ((rA>>2)*72 + 18*qt + (gA>>1))*128 + (rA&3)*32 + (gA&1)*16;
  int g2 = gA & 1;
  int cbase = 18*qt + 9*half;         // this wave's 9 c-chunks
  int pvb0 = ((2*g2    )*72 + cbase)*128 + ((lane&15)>>1)*4;
  int pvb1 = ((2*g2 + 1)*72 + cbase)*128 + ((lane&15)>>1)*4;
  unsigned sel = 0x05040100u + (unsigned)(lane&1)*0x02020202u;
  int h15 = lane & 15;

  f32x4 acc[9];
  #pragma unroll
  for (int c=0;c<9;++c) acc[c] = (f32x4){0.f,0.f,0.f,0.f};

  // ---- prologue: tile0 (all 512 threads convert-write 9 slots each)
  {
    const float4* srcp = (const float4*)hbase;
    #pragma unroll
    for (int i=0;i<9;++i){
      int f = tid + 512*i;
      float4 v = srcp[f];
      *(uint2*)(smem + dst_off_f(f)) =
          make_uint2(cvtpk_bf16(v.x, v.y), cvtpk_bf16(v.z, v.w));
    }
  }
  // memory waves: load tile1 into both batches
  if (w >= 4){
    const uint4v* s1 = (const uint4v*)(hbase + (size_t)18432);
    #pragma unroll
    for (int i=0;i<9;++i){
      uni0[i] = s1[il + 256*i];
      uni1[i] = s1[il + 256*(9+i)];
    }
  }
  __syncthreads();

  float m = -INFINITY, lsum = 0.f;
  float scb = SCALE * cb[h15];

  for (int st=0; st<16; ++st){
    char* tp = (st & 1) ? (smem + 36864) : smem;
    char* tn = (st & 1) ? smem : (smem + 36864);

    if (w < 4){
      // ---- QK: 9 MFMA on bf16 A-frags
      f32x4 d1 = {0.f,0.f,0.f,0.f};
      #pragma unroll
      for (int kk=0;kk<9;++kk){
        uint4v ub = *(const uint4v*)(tp + aoff + 256*kk);
        d1 = __builtin_amdgcn_mfma_f32_16x16x32_bf16(
               __builtin_bit_cast(short8, ub),
               __builtin_bit_cast(short8, uni0[kk]), d1, 0, 0, 0);
      }
      #pragma unroll
      for (int q=0;q<4;++q)
        D1[(w*16 + gA*4 + q)*17 + rA] = d1[q];
    } else if (st+1 < 16){
      // ---- memory: write batch0 of tile t+1; issue batch0 loads for t+2
      #pragma unroll
      for (int i=0;i<9;++i){
        float4 v = __builtin_bit_cast(float4, uni0[i]);
        *(uint2*)(tn + dst_off_f(il + 256*i)) =
            make_uint2(cvtpk_bf16(v.x, v.y), cvtpk_bf16(v.z, v.w));
      }
      if (st+2 < 16){
        const uint4v* s2 = (const uint4v*)(hbase + (size_t)(st+2)*18432);
        #pragma unroll
        for (int i=0;i<9;++i) uni0[i] = s2[il + 256*i];
      }
    }

    LGKM_BAR();                       // D1 ready; batch0 written

    if (w == 0){
      int hh = lane & 15, gg = lane >> 4;
      float v[4];
      #pragma unroll
      for (int q=0;q<4;++q){
        int R = gg*4 + q;
        float raw = D1[R*17+hh] + D1[(16+R)*17+hh]
                  + D1[(32+R)*17+hh] + D1[(48+R)*17+hh];
        v[q] = fmaf(raw, SCALE, scb) + mask_lds[st*16 + R];
      }
      float sm = fmaxf(fmaxf(v[0],v[1]), fmaxf(v[2],v[3]));
      sm = fmaxf(sm, __shfl_xor(sm,16));
      sm = fmaxf(sm, __shfl_xor(sm,32));
      float f = 1.0f;
      if (__any(sm > m + 8.0f)){
        float mn = fmaxf(m, sm);
        f = __expf(m - mn);
        m = mn; lsum *= f;
      }
      if (lane < 16) f_lds[lane] = f;
      float w0 = __expf(v[0] - m), w1 = __expf(v[1] - m);
      float w2 = __expf(v[2] - m), w3 = __expf(v[3] - m);
      lsum += w0 + w1 + w2 + w3;
      wgtA[(gg*16 + hh)*2    ] = cvtpk_bf16(w0, w1);
      wgtA[(gg*16 + hh)*2 + 1] = cvtpk_bf16(w2, w3);
    } else if (w >= 4 && st+1 < 16){
      // ---- memory: write batch1 of tile t+1; issue batch1 loads for t+2
      #pragma unroll
      for (int i=0;i<9;++i){
        float4 v = __builtin_bit_cast(float4, uni1[i]);
        *(uint2*)(tn + dst_off_f(il + 256*(9+i))) =
            make_uint2(cvtpk_bf16(v.x, v.y), cvtpk_bf16(v.z, v.w));
      }
      if (st+2 < 16){
        const uint4v* s2 = (const uint4v*)(hbase + (size_t)(st+2)*18432);
        #pragma unroll
        for (int i=0;i<9;++i) uni1[i] = s2[il + 256*(9+i)];
      }
    }

    LGKM_BAR();                       // wgt/f ready; batch1 written

    // ---- PV: all 8 waves, 9 c-chunks each
    {
      uint4v ua;
      if (gA < 2){
        ua[0] = wgtA[((2*gA  )*16 + h15)*2    ];
        ua[1] = wgtA[((2*gA  )*16 + h15)*2 + 1];
        ua[2] = wgtA[((2*gA+1)*16 + h15)*2    ];
        ua[3] = wgtA[((2*gA+1)*16 + h15)*2 + 1];
      } else {
        ua[0]=0u; ua[1]=0u; ua[2]=0u; ua[3]=0u;
      }
      short8 afrag = __builtin_bit_cast(short8, ua);

      const float4 fv = *(const float4*)(f_lds + gA*4);
      if (fv.x!=1.f || fv.y!=1.f || fv.z!=1.f || fv.w!=1.f){
        #pragma unroll
        for (int c=0;c<9;++c){
          acc[c][0]*=fv.x; acc[c][1]*=fv.y; acc[c][2]*=fv.z; acc[c][3]*=fv.w;
        }
      }
      #pragma unroll
      for (int cl=0; cl<9; ++cl){
        const unsigned* p0 = (const unsigned*)(tp + pvb0 + 128*cl);
        const unsigned* p1 = (const unsigned*)(tp + pvb1 + 128*cl);
        unsigned a0 = p0[0], a1 = p0[8], a2 = p0[16], a3 = p0[24];
        unsigned b0 = p1[0], b1 = p1[8], b2 = p1[16], b3 = p1[24];
        uint4v ub;
        ub[0] = __builtin_amdgcn_perm(a1, a0, sel);
        ub[1] = __builtin_amdgcn_perm(a3, a2, sel);
        ub[2] = __builtin_amdgcn_perm(b1, b0, sel);
        ub[3] = __builtin_amdgcn_perm(b3, b2, sel);
        acc[cl] = __builtin_amdgcn_mfma_f32_16x16x32_bf16(
                    afrag, __builtin_bit_cast(short8, ub), acc[cl], 0, 0, 0);
      }
    }

    LGKM_BAR();                       // tile-t reads done before t+1 overwrites
  }

  if (w == 0){
    float lt = lsum + __shfl_xor(lsum, 16);
    lt += __shfl_xor(lt, 32);
    if (lane < 16){
      size_t o = ((size_t)(b*NSL + sl)*16 + lane)*2;
      part_ml[o] = m; part_ml[o+1] = lt;
    }
  }
  // epilogue: acc[cl][q] = ctx_part[h = gA*4+q][e = 16*(cbase+cl) + h15]
  {
    float* pp = part + ((size_t)(b*NSL + sl))*H*E;
    #pragma unroll
    for (int cl=0; cl<9; ++cl){
      int e = 16*(cbase + cl) + h15;
      #pragma unroll
      for (int q=0;q<4;++q)
        pp[(size_t)(gA*4 + q)*E + e] = acc[cl][q];
    }
  }
}

// ctx[b][h][e] = sum_sl part[b][sl][h][e] * exp(m_sl - M) / L
__global__ void k_ctxred(const float* __restrict__ part, const float* __restrict__ part_ml,
                         float* __restrict__ ctx){
  int idx = blockIdx.x*256 + threadIdx.x;  // < B*H*E
  int b = idx / (H*E); int he = idx % (H*E); int h = he / E;
  float M = -INFINITY, L = 0.f;
  #pragma unroll 4
  for (int c = 0; c < NSL; ++c){
    size_t o = ((size_t)(b*NSL + c)*16 + h)*2;
    float om = part_ml[o], ol = part_ml[o+1];
    float nm = fmaxf(M, om);
    L = L*__expf(M - nm) + ol*__expf(om - nm);
    M = nm;
  }
  float invL = 1.0f / L;
  float s = 0.f;
  #pragma unroll 4
  for (int sl=0; sl<NSL; ++sl){
    float scl = __expf(part_ml[((size_t)(b*NSL + sl)*16 + h)*2] - M) * invL;
    s = fmaf(part[(size_t)(b*NSL+sl)*H*E + he], scl, s);
  }
  ctx[idx] = s;
}

// pooled[b, j] = wv[j,:]·ctx[b, j/72, :] + bv[j]; block = 1 j, 4-way K-split
__global__ __launch_bounds__(256) void k_pool(
    const float* __restrict__ ctx, const float* __restrict__ ipw,
    const float* __restrict__ ipb, float* __restrict__ pooled){
  __shared__ float red[4][32];
  int tid = threadIdx.x, lane = tid & 63, w = tid >> 6;
  int j = blockIdx.x;
  int h = j / HD;
  const float2* wr = (const float2*)(ipw + (size_t)2*E*E + (size_t)j*E);
  float acc[32];
  #pragma unroll
  for (int b_=0;b_<32;++b_) acc[b_]=0.f;
  for (int t=w; t<9; t+=4){
    int e2 = lane + 64*t;
    float2 wv = wr[e2];
    #pragma unroll
    for (int b_=0;b_<32;++b_){
      float2 cv = *(const float2*)(ctx + (size_t)(b_*H + h)*E + 2*e2);
      acc[b_] = fmaf(wv.x, cv.x, fmaf(wv.y, cv.y, acc[b_]));
    }
  }
  #pragma unroll
  for (int b_=0;b_<32;++b_){
    float s = wredsum(acc[b_]);
    if (lane==b_) red[w][b_] = s;
  }
  __syncthreads();
  if (tid < 32){
    float s = red[0][tid] + red[1][tid] + red[2][tid] + red[3][tid];
    pooled[(size_t)tid*E + j] = s + ipb[2*E + j];
  }
}

// resid[b,i] = out_w[i,:]·pooled[b,:] + out_b[i]
__global__ __launch_bounds__(256) void k_outproj(
    const float* __restrict__ pooled, const float* __restrict__ ow,
    const float* __restrict__ ob, float* __restrict__ resid){
  __shared__ float red[4][32];
  int tid = threadIdx.x, lane = tid & 63, w = tid >> 6;
  int i = blockIdx.x;
  const float2* wr = (const float2*)(ow + (size_t)i*E);
  float acc[32];
  #pragma unroll
  for (int b_=0;b_<32;++b_) acc[b_]=0.f;
  for (int t=w; t<9; t+=4){
    int e2 = lane + 64*t;
    float2 wv = wr[e2];
    #pragma unroll
    for (int b_=0;b_<32;++b_){
      float2 pv = *(const float2*)(pooled + (size_t)b_*E + 2*e2);
      acc[b_] = fmaf(wv.x, pv.x, fmaf(wv.y, pv.y, acc[b_]));
    }
  }
  #pragma unroll
  for (int b_=0;b_<32;++b_){
    float s = wredsum(acc[b_]);
    if (lane==b_) red[w][b_] = s;
  }
  __syncthreads();
  if (tid < 32){
    float s = red[0][tid] + red[1][tid] + red[2][tid] + red[3][tid];
    resid[(size_t)tid*E + i] = s + ob[i];
  }
}

__global__ void k_ln(const float* __restrict__ resid, const float* __restrict__ g,
                     const float* __restrict__ be, float* __restrict__ x){
  __shared__ float red[8];
  int b = blockIdx.x, tid = threadIdx.x, lane = tid & 63, w = tid >> 6;
  const float* r = resid + (size_t)b*E;
  float s = 0.f, s2 = 0.f;
  for (int e=tid; e<E; e+=256){ float v = r[e]; s += v; s2 = fmaf(v,v,s2); }
  s = wredsum(s); s2 = wredsum(s2);
  if (lane==0){ red[w]=s; red[4+w]=s2; }
  __syncthreads();
  float S1 = red[0]+red[1]+red[2]+red[3];
  float S2 = red[4]+red[5]+red[6]+red[7];
  float mu  = S1*(1.0f/E);
  float var = S2*(1.0f/E) - mu*mu;
  float inv = rsqrtf(var + 1e-6f);
  for (int e=tid; e<E; e+=256){
    float v = (r[e]-mu)*inv;
    x[(size_t)b*E + e] = v*g[e] + be[e];
  }
}

__device__ __forceinline__ float gelu_tanh(float u){
  float u3 = u*u*u;
  float t = tanhf(0.7978845608028654f*(u + 0.044715f*u3));
  return 0.5f*u*(1.0f+t);
}

// h1[b,i] = gelu(x·fc1_w[i,:]+b1[i]); block = 2 outputs, 4-way K-split
__global__ __launch_bounds__(256) void k_fc1(
    const float* __restrict__ x, const float* __restrict__ w1,
    const float* __restrict__ b1, float* __restrict__ h1){
  __shared__ float red[4][2][32];
  int tid = threadIdx.x, lane = tid & 63, w = tid >> 6;
  int i0 = blockIdx.x*2;           // 2152 blocks
  float acc[2][32];
  #pragma unroll
  for (int ii=0;ii<2;++ii)
    #pragma unroll
    for (int b_=0;b_<32;++b_) acc[ii][b_]=0.f;
  const float2* w1a = (const float2*)(w1 + (size_t)i0*E);
  const float2* w1b = (const float2*)(w1 + (size_t)(i0+1)*E);
  for (int t=w; t<9; t+=4){
    int e2 = lane + 64*t;
    float2 f0 = w1a[e2];
    float2 f1 = w1b[e2];
    #pragma unroll
    for (int b_=0;b_<32;++b_){
      float2 xv = *(const float2*)(x + (size_t)b_*E + 2*e2);
      acc[0][b_] = fmaf(f0.x, xv.x, fmaf(f0.y, xv.y, acc[0][b_]));
      acc[1][b_] = fmaf(f1.x, xv.x, fmaf(f1.y, xv.y, acc[1][b_]));
    }
  }
  #pragma unroll
  for (int ii=0;ii<2;++ii)
    #pragma unroll
    for (int b_=0;b_<32;++b_){
      float s = wredsum(acc[ii][b_]);
      if (lane==b_) red[w][ii][b_] = s;
    }
  __syncthreads();
  if (tid < 64){
    int b_ = tid & 31, ii = tid >> 5;
    float s = red[0][ii][b_] + red[1][ii][b_] + red[2][ii][b_] + red[3][ii][b_];
    h1[(size_t)b_*IDIM + i0 + ii] = gelu_tanh(s + b1[i0+ii]);
  }
}

// out[b,i] = resid + h1·fc2_w[i,:] + b2[i]; block = 2 outputs, 4-way K-split
__global__ __launch_bounds__(256) void k_fc2(
    const float* __restrict__ h1, const float* __restrict__ w2,
    const float* __restrict__ b2, const float* __restrict__ resid,
    float* __restrict__ out){
  __shared__ float red[4][2][32];
  int tid = threadIdx.x, lane = tid & 63, w = tid >> 6;
  int i0 = blockIdx.x*2;           // 576 blocks
  float acc[2][32];
  #pragma unroll
  for (int ii=0;ii<2;++ii)
    #pragma unroll
    for (int b_=0;b_<32;++b_) acc[ii][b_]=0.f;
  for (int t=w; t<68; t+=4){
    int e = lane + 64*t;
    if (e < IDIM){
      float f0 = w2[(size_t)i0*IDIM + e];
      float f1 = w2[(size_t)(i0+1)*IDIM + e];
      #pragma unroll
      for (int b_=0;b_<32;++b_){
        float hvv = h1[(size_t)b_*IDIM + e];
        acc[0][b_] = fmaf(f0, hvv, acc[0][b_]);
        acc[1][b_] = fmaf(f1, hvv, acc[1][b_]);
      }
    }
  }
  #pragma unroll
  for (int ii=0;ii<2;++ii)
    #pragma unroll
    for (int b_=0;b_<32;++b_){
      float s = wredsum(acc[ii][b_]);
      if (lane==b_) red[w][ii][b_] = s;
    }
  __syncthreads();
  if (tid < 64){
    int b_ = tid & 31, ii = tid >> 5;
    float s = red[0][ii][b_] + red[1][ii][b_] + red[2][ii][b_] + red[3][ii][b_];
    int i = i0 + ii;
    out[(size_t)b_*E + i] = resid[(size_t)b_*E + i] + s + b2[i];
  }
}

extern "C" void kernel_launch(void* const* d_in, const int* in_sizes, int n_in,
                              void* d_out, int out_size, void* d_ws, size_t ws_size,
                              hipStream_t stream){
  const float* hidden = (const float*)d_in[0];
  const int*   mask   = (const int*)d_in[1];
  const float* probe  = (const float*)d_in[2];
  const float* ipw    = (const float*)d_in[3];
  const float* ipb    = (const float*)d_in[4];
  const float* ow     = (const float*)d_in[5];
  const float* ob     = (const float*)d_in[6];
  const float* ln_g   = (const float*)d_in[7];
  const float* ln_b   = (const float*)d_in[8];
  const float* w1     = (const float*)d_in[9];
  const float* b1     = (const float*)d_in[10];
  const float* w2     = (const float*)d_in[11];
  const float* b2     = (const float*)d_in[12];
  float* out = (float*)d_out;
  float* ws  = (float*)d_ws;

  size_t off = 0;
  float* q  = ws + off; off += E;
  float* cb = ws + off; off += 16;
  unsigned short* qkfrag = (unsigned short*)(ws + off); off += 9216;
  float* part_ml = ws + off; off += 32*NSL*16*2;
  float* part    = ws + off; off += (size_t)B*NSL*H*E;  // 37.7 MB
  float* ctx     = ws + off; off += (size_t)B*H*E;
  float* pooled  = ws + off; off += (size_t)B*E;
  float* resid   = ws + off; off += (size_t)B*E;
  float* x       = ws + off; off += (size_t)B*E;
  float* h1      = ws + off;

  k_q       <<<288, 256, 0, stream>>>(probe, ipw, ipb, q);
  k_qk      <<<72, 256, 0, stream>>>(q, ipw, ipb, qkfrag, cb);
  k_fused   <<<B*NSL, 512, 0, stream>>>(hidden, qkfrag, cb, mask, part, part_ml);
  k_ctxred  <<<2304, 256, 0, stream>>>(part, part_ml, ctx);
  k_pool    <<<1152, 256, 0, stream>>>(ctx, ipw, ipb, pooled);
  k_outproj <<<1152, 256, 0, stream>>>(pooled, ow, ob, resid);
  k_ln      <<<32, 256, 0, stream>>>(resid, ln_g, ln_b, x);
  k_fc1     <<<2152, 256, 0, stream>>>(x, w1, b1, h1);
  k_fc2     <<<576, 256, 0, stream>>>(h1, w2, b2, resid, out);
}

// Round 15
// 303.823 us; speedup vs baseline: 1.4647x; 1.4647x over previous
//
#include <hip/hip_runtime.h>
#include <math.h>

#define E 1152
#define H 16
#define HD 72
#define B 32
#define S 4096
#define IDIM 4304
#define NSL 16

#define NEGF (-3.402823466e38f)
#define SCALE 0.1178511301977579f  // 1/sqrt(72)

typedef short short8 __attribute__((ext_vector_type(8)));
typedef float f32x4 __attribute__((ext_vector_type(4)));
typedef unsigned int uint4v __attribute__((ext_vector_type(4)));

#define LGKM_BAR() do { asm volatile("s_waitcnt lgkmcnt(0)" ::: "memory"); \
                        __builtin_amdgcn_s_barrier(); } while(0)

__device__ __forceinline__ unsigned int cvtpk_bf16(float lo, float hi){
  unsigned int r;
  asm("v_cvt_pk_bf16_f32 %0, %1, %2" : "=v"(r) : "v"(lo), "v"(hi));
  return r;
}

__device__ __forceinline__ unsigned short f2bf(float x){
  unsigned int u = __float_as_uint(x);
  u = (u + 0x7fffu + ((u >> 16) & 1u)) >> 16;   // RNE
  return (unsigned short)u;
}

// bf16 tile dest byte offset for staging slot (f = tid + 256*i); rematerializable
__device__ __forceinline__ int dst_off(int tid, int i){
  int f = tid + 256*i;
  int r = f / 288;
  int c4 = f - r*288;
  return ((r>>2)*72 + (c4>>2))*128 + (r&3)*32 + (c4&3)*8;
}

__device__ __forceinline__ float wredsum(float v){
  v += __shfl_xor(v,32); v += __shfl_xor(v,16); v += __shfl_xor(v,8);
  v += __shfl_xor(v,4);  v += __shfl_xor(v,2);  v += __shfl_xor(v,1);
  return v;
}

// q[j] = probe . wq[j,:] + bq[j]   (float2 loads)
__global__ void k_q(const float* __restrict__ probe, const float* __restrict__ ipw,
                    const float* __restrict__ ipb, float* __restrict__ q){
  int tid = threadIdx.x, lane = tid & 63, w = tid >> 6;
  int j = blockIdx.x*4 + w;
  const float2* wr = (const float2*)(ipw + (size_t)j*E);
  const float2* pr = (const float2*)probe;
  float s = 0.f;
  #pragma unroll
  for (int t=0;t<9;++t){
    int e2 = lane + 64*t;
    float2 a = pr[e2], b = wr[e2];
    s = fmaf(a.x, b.x, fmaf(a.y, b.y, s));
  }
  s = wredsum(s);
  if (lane==0) q[j] = s + ipb[j];
}

// qk -> bf16 B-frag order; 288 blocks x 64 outputs, 4-way d-split + LDS combine
__global__ __launch_bounds__(256) void k_qk(
    const float* __restrict__ q, const float* __restrict__ ipw,
    const float* __restrict__ ipb, unsigned short* __restrict__ qkfrag,
    float* __restrict__ cb){
  __shared__ float red[3][64];
  int tid = threadIdx.x, lane = tid & 63, w = tid >> 6;
  int idx = blockIdx.x*64 + lane;        // < H*E
  int h = idx / E, e = idx - h*E;
  const float* qh = q + h*HD + 18*w;
  const float* col = ipw + (size_t)(E + h*HD + 18*w)*E + e;
  float s = 0.f;
  #pragma unroll
  for (int d = 0; d < 18; ++d)
    s = fmaf(qh[d], col[(size_t)d*E], s);
  if (w) red[w-1][lane] = s;
  __syncthreads();
  if (w == 0){
    s += red[0][lane] + red[1][lane] + red[2][lane];
    int kk = e >> 5, g = (e >> 3) & 3, j = e & 7;
    qkfrag[(size_t)kk*512 + (g*16 + h)*8 + j] = f2bf(s);
    if (blockIdx.x == 0 && lane < 16){
      float c = 0.f;
      for (int d=0; d<HD; ++d) c = fmaf(q[lane*HD+d], ipb[E + lane*HD + d], c);
      cb[lane] = c;
    }
  }
}

// ---------------- fused flash pass, v7: constant-shift softmax (m=8 const,
// mathematically identical after normalization), softmax computed per-lane
// (redundant across waves) directly from D1 -> ONE barrier removed per stage,
// no wave0 serial section, no rescale ever.
__global__ __launch_bounds__(256) void k_fused(
    const float* __restrict__ hidden, const unsigned short* __restrict__ qkfrag,
    const float* __restrict__ cb, const int* __restrict__ mask,
    float* __restrict__ part, float* __restrict__ lsums){
  __shared__ __attribute__((aligned(16))) char smem[79104];
  float* D1       = (float*)(smem + 73728);   // [4][16][17]
  float* mask_lds = (float*)(smem + 78080);   // [256]

  int tid = threadIdx.x, lane = tid & 63, w = tid >> 6;
  int b = blockIdx.x >> 4, sl = blockIdx.x & 15;
  int s0 = sl * 256;

  mask_lds[tid] = (1.0f - (float)mask[(size_t)b*S + s0 + tid]) * NEGF;

  short8 qkf[9];
  {
    const short8* qf = (const short8*)qkfrag;
    #pragma unroll
    for (int kk=0;kk<9;++kk) qkf[kk] = qf[(9*w + kk)*64 + lane];
  }

  int rA = lane & 15, gA = lane >> 4;
  int aoff = ((rA>>2)*72 + 18*w + (gA>>1))*128 + (rA&3)*32 + (gA&1)*16;
  int g2 = gA & 1;
  int pvb0 = ((2*g2    )*72 + 18*w)*128 + ((lane&15)>>1)*4;
  int pvb1 = ((2*g2 + 1)*72 + 18*w)*128 + ((lane&15)>>1)*4;
  unsigned sel = 0x05040100u + (unsigned)(lane&1)*0x02020202u;
  int h15 = lane & 15;

  f32x4 acc[18];
  #pragma unroll
  for (int c=0;c<18;++c) acc[c] = (f32x4){0.f,0.f,0.f,0.f};

  float lsum = 0.f;
  float scb8 = SCALE * cb[h15] - 8.0f;    // constant-shift softmax
  const float* hbase = hidden + ((size_t)b*S + s0)*E;

  // ---- prologue: stage 0 -> tile0 (bf16)
  {
    const float4* srcp = (const float4*)hbase;
    #pragma unroll
    for (int i=0;i<18;++i){
      float4 v = srcp[tid + 256*i];
      *(uint2*)(smem + dst_off(tid, i)) =
          make_uint2(cvtpk_bf16(v.x, v.y), cvtpk_bf16(v.z, v.w));
    }
  }

  for (int st=0; st<16; ++st){
    __syncthreads();                       // tile[st&1] ready
    char* tp = (st & 1) ? (smem + 36864) : smem;
    char* tn = (st & 1) ? smem : (smem + 36864);
    const float4* srcp = (const float4*)(hbase + (size_t)(st+1)*18432);

    float4 stg0[9];
    if (st+1 < 16){
      #pragma unroll
      for (int i=0;i<9;++i) stg0[i] = srcp[tid + 256*i];
    }
    __builtin_amdgcn_sched_barrier(0);

    // ---- QK: 9 MFMA on bf16 A-frags
    f32x4 d1 = {0.f,0.f,0.f,0.f};
    #pragma unroll
    for (int kk=0;kk<9;++kk){
      uint4v ub = *(const uint4v*)(tp + aoff + 256*kk);
      d1 = __builtin_amdgcn_mfma_f32_16x16x32_bf16(
             __builtin_bit_cast(short8, ub), qkf[kk], d1, 0, 0, 0);
    }
    #pragma unroll
    for (int q=0;q<4;++q)
      D1[(w*16 + gA*4 + q)*17 + rA] = d1[q];

    LGKM_BAR();                            // D1 ready (only barrier besides top)

    // ---- per-lane softmax: lane (gA<2, h15) builds its PV A-frag directly
    uint4v ua; ua[0]=0u; ua[1]=0u; ua[2]=0u; ua[3]=0u;
    if (gA < 2){
      float wl[8];
      #pragma unroll
      for (int j=0;j<8;++j){
        int R = 8*gA + j;
        float raw = D1[R*17+h15] + D1[(16+R)*17+h15]
                  + D1[(32+R)*17+h15] + D1[(48+R)*17+h15];
        wl[j] = __expf(fmaf(raw, SCALE, scb8) + mask_lds[st*16 + R]);
      }
      ua[0] = cvtpk_bf16(wl[0], wl[1]);
      ua[1] = cvtpk_bf16(wl[2], wl[3]);
      ua[2] = cvtpk_bf16(wl[4], wl[5]);
      ua[3] = cvtpk_bf16(wl[6], wl[7]);
      if (w == 0)
        lsum += ((wl[0]+wl[1]) + (wl[2]+wl[3])) + ((wl[4]+wl[5]) + (wl[6]+wl[7]));
    }
    short8 afrag = __builtin_bit_cast(short8, ua);

    // ---- write batch0 of next tile (stg0 issued ~QK+softmax ago), issue stg1
    if (st+1 < 16){
      #pragma unroll
      for (int i=0;i<9;++i){
        *(uint2*)(tn + dst_off(tid, i)) =
            make_uint2(cvtpk_bf16(stg0[i].x, stg0[i].y),
                       cvtpk_bf16(stg0[i].z, stg0[i].w));
      }
    }
    float4 stg1[9];
    if (st+1 < 16){
      #pragma unroll
      for (int i=0;i<9;++i) stg1[i] = srcp[tid + 256*i + 2304];
    }
    __builtin_amdgcn_sched_barrier(0);

    // ---- PV: 18 MFMA, B = tile rows via ds_read_b32 + v_perm
    #pragma unroll
    for (int c=0;c<18;++c){
      const unsigned* p0 = (const unsigned*)(tp + pvb0 + 128*c);
      const unsigned* p1 = (const unsigned*)(tp + pvb1 + 128*c);
      unsigned a0 = p0[0], a1 = p0[8], a2 = p0[16], a3 = p0[24];
      unsigned b0 = p1[0], b1 = p1[8], b2 = p1[16], b3 = p1[24];
      uint4v ub;
      ub[0] = __builtin_amdgcn_perm(a1, a0, sel);
      ub[1] = __builtin_amdgcn_perm(a3, a2, sel);
      ub[2] = __builtin_amdgcn_perm(b1, b0, sel);
      ub[3] = __builtin_amdgcn_perm(b3, b2, sel);
      acc[c] = __builtin_amdgcn_mfma_f32_16x16x32_bf16(
                 afrag, __builtin_bit_cast(short8, ub), acc[c], 0, 0, 0);
    }
    __builtin_amdgcn_sched_barrier(0);

    // ---- write batch1 (latency covered by PV)
    if (st+1 < 16){
      #pragma unroll
      for (int i=0;i<9;++i){
        *(uint2*)(tn + dst_off(tid, 9+i)) =
            make_uint2(cvtpk_bf16(stg1[i].x, stg1[i].y),
                       cvtpk_bf16(stg1[i].z, stg1[i].w));
      }
    }
  }

  if (w == 0){
    float lt = lsum + __shfl_xor(lsum, 16);
    lt += __shfl_xor(lt, 32);
    if (lane < 16)
      lsums[(size_t)(b*NSL + sl)*16 + lane] = lt;
  }
  // epilogue: acc[c][q] = ctx_part[h = gA*4+q][e = 16*(18w+c) + h15]
  {
    float* pp = part + ((size_t)(b*NSL + sl))*H*E;
    #pragma unroll
    for (int c=0;c<18;++c){
      int e = 16*(18*w + c) + h15;
      #pragma unroll
      for (int q=0;q<4;++q)
        pp[(size_t)(gA*4 + q)*E + e] = acc[c][q];
    }
  }
}

// ctx[b][h][e] = (sum_sl part[b][sl][h][e]) / (sum_sl l[b][sl][h])
__global__ void k_ctxred(const float* __restrict__ part, const float* __restrict__ lsums,
                         float* __restrict__ ctx){
  int idx = blockIdx.x*256 + threadIdx.x;  // < B*H*E
  int b = idx / (H*E); int he = idx % (H*E); int h = he / E;
  float L = 0.f;
  #pragma unroll 4
  for (int c = 0; c < NSL; ++c)
    L += lsums[(size_t)(b*NSL + c)*16 + h];
  float s = 0.f;
  #pragma unroll 4
  for (int sl=0; sl<NSL; ++sl)
    s += part[(size_t)(b*NSL+sl)*H*E + he];
  ctx[idx] = s / L;
}

// pooled[b, j] = wv[j,:]·ctx[b, j/72, :] + bv[j]; block = 1 j, 4-way K-split
__global__ __launch_bounds__(256) void k_pool(
    const float* __restrict__ ctx, const float* __restrict__ ipw,
    const float* __restrict__ ipb, float* __restrict__ pooled){
  __shared__ float red[4][32];
  int tid = threadIdx.x, lane = tid & 63, w = tid >> 6;
  int j = blockIdx.x;
  int h = j / HD;
  const float2* wr = (const float2*)(ipw + (size_t)2*E*E + (size_t)j*E);
  float acc[32];
  #pragma unroll
  for (int b_=0;b_<32;++b_) acc[b_]=0.f;
  for (int t=w; t<9; t+=4){
    int e2 = lane + 64*t;
    float2 wv = wr[e2];
    #pragma unroll
    for (int b_=0;b_<32;++b_){
      float2 cv = *(const float2*)(ctx + (size_t)(b_*H + h)*E + 2*e2);
      acc[b_] = fmaf(wv.x, cv.x, fmaf(wv.y, cv.y, acc[b_]));
    }
  }
  #pragma unroll
  for (int b_=0;b_<32;++b_){
    float s = wredsum(acc[b_]);
    if (lane==b_) red[w][b_] = s;
  }
  __syncthreads();
  if (tid < 32){
    float s = red[0][tid] + red[1][tid] + red[2][tid] + red[3][tid];
    pooled[(size_t)tid*E + j] = s + ipb[2*E + j];
  }
}

// resid[b,i] = out_w[i,:]·pooled[b,:] + out_b[i]
__global__ __launch_bounds__(256) void k_outproj(
    const float* __restrict__ pooled, const float* __restrict__ ow,
    const float* __restrict__ ob, float* __restrict__ resid){
  __shared__ float red[4][32];
  int tid = threadIdx.x, lane = tid & 63, w = tid >> 6;
  int i = blockIdx.x;
  const float2* wr = (const float2*)(ow + (size_t)i*E);
  float acc[32];
  #pragma unroll
  for (int b_=0;b_<32;++b_) acc[b_]=0.f;
  for (int t=w; t<9; t+=4){
    int e2 = lane + 64*t;
    float2 wv = wr[e2];
    #pragma unroll
    for (int b_=0;b_<32;++b_){
      float2 pv = *(const float2*)(pooled + (size_t)b_*E + 2*e2);
      acc[b_] = fmaf(wv.x, pv.x, fmaf(wv.y, pv.y, acc[b_]));
    }
  }
  #pragma unroll
  for (int b_=0;b_<32;++b_){
    float s = wredsum(acc[b_]);
    if (lane==b_) red[w][b_] = s;
  }
  __syncthreads();
  if (tid < 32){
    float s = red[0][tid] + red[1][tid] + red[2][tid] + red[3][tid];
    resid[(size_t)tid*E + i] = s + ob[i];
  }
}

__global__ void k_ln(const float* __restrict__ resid, const float* __restrict__ g,
                     const float* __restrict__ be, float* __restrict__ x){
  __shared__ float red[8];
  int b = blockIdx.x, tid = threadIdx.x, lane = tid & 63, w = tid >> 6;
  const float* r = resid + (size_t)b*E;
  float s = 0.f, s2 = 0.f;
  for (int e=tid; e<E; e+=256){ float v = r[e]; s += v; s2 = fmaf(v,v,s2); }
  s = wredsum(s); s2 = wredsum(s2);
  if (lane==0){ red[w]=s; red[4+w]=s2; }
  __syncthreads();
  float S1 = red[0]+red[1]+red[2]+red[3];
  float S2 = red[4]+red[5]+red[6]+red[7];
  float mu  = S1*(1.0f/E);
  float var = S2*(1.0f/E) - mu*mu;
  float inv = rsqrtf(var + 1e-6f);
  for (int e=tid; e<E; e+=256){
    float v = (r[e]-mu)*inv;
    x[(size_t)b*E + e] = v*g[e] + be[e];
  }
}

__device__ __forceinline__ float gelu_tanh(float u){
  float u3 = u*u*u;
  float t = tanhf(0.7978845608028654f*(u + 0.044715f*u3));
  return 0.5f*u*(1.0f+t);
}

// h1[b,i] = gelu(x·fc1_w[i,:]+b1[i]); block = 2 outputs, 4-way K-split
__global__ __launch_bounds__(256) void k_fc1(
    const float* __restrict__ x, const float* __restrict__ w1,
    const float* __restrict__ b1, float* __restrict__ h1){
  __shared__ float red[4][2][32];
  int tid = threadIdx.x, lane = tid & 63, w = tid >> 6;
  int i0 = blockIdx.x*2;           // 2152 blocks
  float acc[2][32];
  #pragma unroll
  for (int ii=0;ii<2;++ii)
    #pragma unroll
    for (int b_=0;b_<32;++b_) acc[ii][b_]=0.f;
  const float2* w1a = (const float2*)(w1 + (size_t)i0*E);
  const float2* w1b = (const float2*)(w1 + (size_t)(i0+1)*E);
  for (int t=w; t<9; t+=4){
    int e2 = lane + 64*t;
    float2 f0 = w1a[e2];
    float2 f1 = w1b[e2];
    #pragma unroll
    for (int b_=0;b_<32;++b_){
      float2 xv = *(const float2*)(x + (size_t)b_*E + 2*e2);
      acc[0][b_] = fmaf(f0.x, xv.x, fmaf(f0.y, xv.y, acc[0][b_]));
      acc[1][b_] = fmaf(f1.x, xv.x, fmaf(f1.y, xv.y, acc[1][b_]));
    }
  }
  #pragma unroll
  for (int ii=0;ii<2;++ii)
    #pragma unroll
    for (int b_=0;b_<32;++b_){
      float s = wredsum(acc[ii][b_]);
      if (lane==b_) red[w][ii][b_] = s;
    }
  __syncthreads();
  if (tid < 64){
    int b_ = tid & 31, ii = tid >> 5;
    float s = red[0][ii][b_] + red[1][ii][b_] + red[2][ii][b_] + red[3][ii][b_];
    h1[(size_t)b_*IDIM + i0 + ii] = gelu_tanh(s + b1[i0+ii]);
  }
}

// out[b,i] = resid + h1·fc2_w[i,:] + b2[i]; block = 2 outputs, 4-way K-split
__global__ __launch_bounds__(256) void k_fc2(
    const float* __restrict__ h1, const float* __restrict__ w2,
    const float* __restrict__ b2, const float* __restrict__ resid,
    float* __restrict__ out){
  __shared__ float red[4][2][32];
  int tid = threadIdx.x, lane = tid & 63, w = tid >> 6;
  int i0 = blockIdx.x*2;           // 576 blocks
  float acc[2][32];
  #pragma unroll
  for (int ii=0;ii<2;++ii)
    #pragma unroll
    for (int b_=0;b_<32;++b_) acc[ii][b_]=0.f;
  for (int t=w; t<68; t+=4){
    int e = lane + 64*t;
    if (e < IDIM){
      float f0 = w2[(size_t)i0*IDIM + e];
      float f1 = w2[(size_t)(i0+1)*IDIM + e];
      #pragma unroll
      for (int b_=0;b_<32;++b_){
        float hvv = h1[(size_t)b_*IDIM + e];
        acc[0][b_] = fmaf(f0, hvv, acc[0][b_]);
        acc[1][b_] = fmaf(f1, hvv, acc[1][b_]);
      }
    }
  }
  #pragma unroll
  for (int ii=0;ii<2;++ii)
    #pragma unroll
    for (int b_=0;b_<32;++b_){
      float s = wredsum(acc[ii][b_]);
      if (lane==b_) red[w][ii][b_] = s;
    }
  __syncthreads();
  if (tid < 64){
    int b_ = tid & 31, ii = tid >> 5;
    float s = red[0][ii][b_] + red[1][ii][b_] + red[2][ii][b_] + red[3][ii][b_];
    int i = i0 + ii;
    out[(size_t)b_*E + i] = resid[(size_t)b_*E + i] + s + b2[i];
  }
}

extern "C" void kernel_launch(void* const* d_in, const int* in_sizes, int n_in,
                              void* d_out, int out_size, void* d_ws, size_t ws_size,
                              hipStream_t stream){
  const float* hidden = (const float*)d_in[0];
  const int*   mask   = (const int*)d_in[1];
  const float* probe  = (const float*)d_in[2];
  const float* ipw    = (const float*)d_in[3];
  const float* ipb    = (const float*)d_in[4];
  const float* ow     = (const float*)d_in[5];
  const float* ob     = (const float*)d_in[6];
  const float* ln_g   = (const float*)d_in[7];
  const float* ln_b   = (const float*)d_in[8];
  const float* w1     = (const float*)d_in[9];
  const float* b1     = (const float*)d_in[10];
  const float* w2     = (const float*)d_in[11];
  const float* b2     = (const float*)d_in[12];
  float* out = (float*)d_out;
  float* ws  = (float*)d_ws;

  size_t off = 0;
  float* q  = ws + off; off += E;
  float* cb = ws + off; off += 16;
  unsigned short* qkfrag = (unsigned short*)(ws + off); off += 9216;
  float* lsums = ws + off; off += 32*NSL*16;
  float* part    = ws + off; off += (size_t)B*NSL*H*E;  // 37.7 MB
  float* ctx     = ws + off; off += (size_t)B*H*E;
  float* pooled  = ws + off; off += (size_t)B*E;
  float* resid   = ws + off; off += (size_t)B*E;
  float* x       = ws + off; off += (size_t)B*E;
  float* h1      = ws + off;

  k_q       <<<288, 256, 0, stream>>>(probe, ipw, ipb, q);
  k_qk      <<<288, 256, 0, stream>>>(q, ipw, ipb, qkfrag, cb);
  k_fused   <<<B*NSL, 256, 0, stream>>>(hidden, qkfrag, cb, mask, part, lsums);
  k_ctxred  <<<2304, 256, 0, stream>>>(part, lsums, ctx);
  k_pool    <<<1152, 256, 0, stream>>>(ctx, ipw, ipb, pooled);
  k_outproj <<<1152, 256, 0, stream>>>(pooled, ow, ob, resid);
  k_ln      <<<32, 256, 0, stream>>>(resid, ln_g, ln_b, x);
  k_fc1     <<<2152, 256, 0, stream>>>(x, w1, b1, h1);
  k_fc2     <<<576, 256, 0, stream>>>(h1, w2, b2, resid, out);
}